// Round 2
// baseline (98837.750 us; speedup 1.0000x reference)
//
#include <hip/hip_runtime.h>
#include <cstddef>

// SafetyReflexSNN: 5-layer LIF SNN, B=128, T=512.
//
// ROUND 13: time-CHUNKED batched rewrite. Round 12's batched path needed
// 537 MB workspace and never ran (ws_size < 537 MB -> fallback, dur
// unchanged). This version processes T in chunks of Tc timesteps chosen at
// launch time to fit ws_size (Tc in {512,...,2}; Tc=2 needs 4.59 MB which
// is GUARANTEED to fit since the round-11 path passed using 5.64 MB).
//
// Per chunk: L0 gemm -> scan0 -> L1 gemm -> scan1 -> L2a gemm ->
// rec2 x Tc (serial, fused LIF) -> L3 gemm -> scan3 -> L4 gemm -> scan_out.
// Membrane potentials v0..vo, counts, and s2[last] carry across chunks.
//
// NUMERICS (inherited, absmax 0.0): per output element the op sequence is
// IDENTICAL to the round-11 passing kernel: ascending-k fmaf chain; K=1024
// folds once at k=512 via tot=__fadd_rn(tot,pan); final __fadd_rn(tot,pan);
// layer-2 combine = one __fadd_rn(cur2a, rec); LIF = __fmul_rn / __fadd_rn
// / __fsub_rn (no contraction); counts accumulated in ascending t.

#define NB 128
#define NT 512

// ---------------------------------------------------------------------------
// ------------------------- CHUNKED BATCHED PATH ----------------------------
// ---------------------------------------------------------------------------

// ---- big feedforward GEMM: C[m][o] = sum_k A[m][k]*W[o][k] ----
// BM=64 (blockIdx.y), BN=128 (blockIdx.x), BK=32, 256 threads, 4m x 8o.
// XMAP: A is the input x [B][T=512][512]; row m of the chunk maps to
// global row (m>>tcshift)*512 + t0 + (m & (Tc-1)).

__device__ __forceinline__ void bg_stage(
    float (&As)[2][32][68], float (&Ws)[2][32][132], int b, int sk, int sr,
    const float4& a0, const float4& a1, const float4& w0, const float4& w1,
    const float4& w2, const float4& w3)
{
  As[b][sk+0][sr] = a0.x; As[b][sk+1][sr] = a0.y; As[b][sk+2][sr] = a0.z; As[b][sk+3][sr] = a0.w;
  As[b][sk+0][sr+32] = a1.x; As[b][sk+1][sr+32] = a1.y; As[b][sk+2][sr+32] = a1.z; As[b][sk+3][sr+32] = a1.w;
  Ws[b][sk+0][sr] = w0.x; Ws[b][sk+1][sr] = w0.y; Ws[b][sk+2][sr] = w0.z; Ws[b][sk+3][sr] = w0.w;
  Ws[b][sk+0][sr+32] = w1.x; Ws[b][sk+1][sr+32] = w1.y; Ws[b][sk+2][sr+32] = w1.z; Ws[b][sk+3][sr+32] = w1.w;
  Ws[b][sk+0][sr+64] = w2.x; Ws[b][sk+1][sr+64] = w2.y; Ws[b][sk+2][sr+64] = w2.z; Ws[b][sk+3][sr+64] = w2.w;
  Ws[b][sk+0][sr+96] = w3.x; Ws[b][sk+1][sr+96] = w3.y; Ws[b][sk+2][sr+96] = w3.z; Ws[b][sk+3][sr+96] = w3.w;
}

template<int K, bool FOLD, bool XMAP>
__global__ __launch_bounds__(256, 3) void big_gemm(
    const float* __restrict__ A, const float* __restrict__ W,
    float* __restrict__ C, int N, int t0, int tcshift)
{
  __shared__ float As[2][32][68];
  __shared__ float Ws[2][32][132];
  const int tid = threadIdx.x;
  const int m0 = blockIdx.y << 6;
  const int o0 = blockIdx.x << 7;
  const int sk = (tid & 7) << 2;   // staging k offset 0,4..28
  const int sr = tid >> 3;         // staging row 0..31
  const int tm = (tid >> 4) << 2;  // compute m 0..60
  const int to = (tid & 15) << 2;  // compute o 0..60 (and +64)

  size_t offA0, offA1;
  if (XMAP) {
    const int tcmask = (1 << tcshift) - 1;
    const int mA = m0 + sr, mB = m0 + sr + 32;
    offA0 = ((size_t)(mA >> tcshift) * NT + t0 + (mA & tcmask)) * (size_t)K;
    offA1 = ((size_t)(mB >> tcshift) * NT + t0 + (mB & tcmask)) * (size_t)K;
  } else {
    offA0 = (size_t)(m0 + sr) * K;
    offA1 = (size_t)(m0 + sr + 32) * K;
  }
  const float* ArA = A + offA0 + sk;
  const float* ArB = A + offA1 + sk;
  const float* Wp  = W + (size_t)(o0 + sr) * K + sk;
  const size_t R32 = (size_t)32 * K;

  float pan[4][8], tot[4][8];
#pragma unroll
  for (int i = 0; i < 4; ++i)
#pragma unroll
    for (int j = 0; j < 8; ++j) { pan[i][j] = 0.f; tot[i][j] = 0.f; }

  constexpr int NKT = K >> 5;

  // prologue: tile 0 -> buf 0
  {
    float4 a0 = *(const float4*)(ArA);
    float4 a1 = *(const float4*)(ArB);
    float4 w0 = *(const float4*)(Wp);
    float4 w1 = *(const float4*)(Wp + R32);
    float4 w2 = *(const float4*)(Wp + 2 * R32);
    float4 w3 = *(const float4*)(Wp + 3 * R32);
    bg_stage(As, Ws, 0, sk, sr, a0, a1, w0, w1, w2, w3);
  }
  __syncthreads();

  int cb = 0;
  for (int kt = 0; kt < NKT; ++kt) {
    float4 na0, na1, nw0, nw1, nw2, nw3;
    if (kt + 1 < NKT) {  // issue next tile's global loads early
      const int ko = (kt + 1) << 5;
      na0 = *(const float4*)(ArA + ko);
      na1 = *(const float4*)(ArB + ko);
      nw0 = *(const float4*)(Wp + ko);
      nw1 = *(const float4*)(Wp + ko + R32);
      nw2 = *(const float4*)(Wp + ko + 2 * R32);
      nw3 = *(const float4*)(Wp + ko + 3 * R32);
    }
    if (FOLD && kt == 16) {  // kc-panel boundary at k=512: fold, restart chain
#pragma unroll
      for (int i = 0; i < 4; ++i)
#pragma unroll
        for (int j = 0; j < 8; ++j) {
          tot[i][j] = __fadd_rn(tot[i][j], pan[i][j]);
          pan[i][j] = 0.f;
        }
    }
#pragma unroll
    for (int k = 0; k < 32; ++k) {
      const float4 av  = *(const float4*)&As[cb][k][tm];
      const float4 wv0 = *(const float4*)&Ws[cb][k][to];
      const float4 wv1 = *(const float4*)&Ws[cb][k][to + 64];
      const float aa[4] = {av.x, av.y, av.z, av.w};
      const float ww[8] = {wv0.x, wv0.y, wv0.z, wv0.w, wv1.x, wv1.y, wv1.z, wv1.w};
#pragma unroll
      for (int i = 0; i < 4; ++i)
#pragma unroll
        for (int j = 0; j < 8; ++j)
          pan[i][j] = fmaf(aa[i], ww[j], pan[i][j]);  // one chain per element
    }
    __syncthreads();
    if (kt + 1 < NKT) {
      bg_stage(As, Ws, cb ^ 1, sk, sr, na0, na1, nw0, nw1, nw2, nw3);
    }
    __syncthreads();
    cb ^= 1;
  }

  // epilogue: fold last panel, write C
#pragma unroll
  for (int i = 0; i < 4; ++i) {
    float4 r0, r1;
    r0.x = __fadd_rn(tot[i][0], pan[i][0]);
    r0.y = __fadd_rn(tot[i][1], pan[i][1]);
    r0.z = __fadd_rn(tot[i][2], pan[i][2]);
    r0.w = __fadd_rn(tot[i][3], pan[i][3]);
    r1.x = __fadd_rn(tot[i][4], pan[i][4]);
    r1.y = __fadd_rn(tot[i][5], pan[i][5]);
    r1.z = __fadd_rn(tot[i][6], pan[i][6]);
    r1.w = __fadd_rn(tot[i][7], pan[i][7]);
    float* Crow = C + (size_t)(m0 + tm + i) * N + o0 + to;
    *(float4*)Crow = r0;
    *(float4*)(Crow + 64) = r1;
  }
}

// ---- LIF scan over the chunk: thread = (b, n), v carried in state ----
template<int N>
__global__ __launch_bounds__(256) void scan_kernel(
    const float* __restrict__ cur, float* __restrict__ sp,
    float* __restrict__ vstate, float alpha, float vth, int tc)
{
  const int idx = blockIdx.x * 256 + threadIdx.x;
  const int b = idx / N;
  const int n = idx & (N - 1);
  const float* cp = cur + (size_t)b * tc * N + n;
  float* op = sp + (size_t)b * tc * N + n;
  float v = vstate[idx];
#pragma unroll 4
  for (int tl = 0; tl < tc; ++tl) {
    float c = cp[(size_t)tl * N];
    float vv = __fadd_rn(__fmul_rn(alpha, v), c);
    float s = (vv >= vth) ? 1.0f : 0.0f;
    v = __fmul_rn(vv, __fsub_rn(1.0f, s));
    op[(size_t)tl * N] = s;
  }
  vstate[idx] = v;
}

// ---- output-layer scan: spikes -> out, counts carried in state ----
__global__ __launch_bounds__(256) void scan_out_kernel(
    const float* __restrict__ cur, float* __restrict__ out,
    float* __restrict__ vstate, float* __restrict__ cntstate,
    int t0, int tc)
{
  const int idx = blockIdx.x * 256 + threadIdx.x;  // 16384 = 128*128
  const int b = idx >> 7;
  const int o = idx & 127;
  const float* cp = cur + (size_t)b * tc * 128 + o;
  float v = vstate[idx], cnt = cntstate[idx];
#pragma unroll 4
  for (int tl = 0; tl < tc; ++tl) {
    float c = cp[(size_t)tl * 128];
    float vv = __fadd_rn(__fmul_rn(0.82f, v), c);
    float s = (vv >= 0.8f) ? 1.0f : 0.0f;
    v = __fmul_rn(vv, __fsub_rn(1.0f, s));
    out[((size_t)b * NT + t0 + tl) * 128 + o] = s;
    cnt = __fadd_rn(cnt, s);  // integer-exact, ascending t
  }
  vstate[idx] = v;
  cntstate[idx] = cnt;
}

// ---- recurrent layer-2 step: rec = s2_prev @ W2b^T (K=1024, fold@512),
//      fused +cur2a and LIF. 8x64 tile; waves 0-3 = panel k<512, 4-7 k>=512.
__device__ __forceinline__ void r2_stage(
    float (&As)[2][2][32][12], float (&Ws)[2][2][32][66], int p, int b,
    int ak, int am, int wk, int wr, float a, const float4& w0, const float4& w1)
{
  As[p][b][ak][am] = a;
  Ws[p][b][wk+0][wr] = w0.x; Ws[p][b][wk+1][wr] = w0.y;
  Ws[p][b][wk+2][wr] = w0.z; Ws[p][b][wk+3][wr] = w0.w;
  Ws[p][b][wk+0][wr+32] = w1.x; Ws[p][b][wk+1][wr+32] = w1.y;
  Ws[p][b][wk+2][wr+32] = w1.z; Ws[p][b][wk+3][wr+32] = w1.w;
}

__global__ __launch_bounds__(512, 2) void rec2_kernel(
    const float* __restrict__ curA,   // cur2a chunk base + tl*1024 (stride bStride per b)
    const float* __restrict__ W2b,    // [1024][1024]
    const float* __restrict__ prev,   // s2 at t-1: chunk row or sprev carry
    size_t prevStride,                // per-b stride of prev
    float* __restrict__ sOut,         // s2 out: chunk base + tl*1024
    size_t bStride,                   // per-b stride of chunk buffers (Tc*1024)
    float* __restrict__ sPrevOut, int writePrev,
    float* __restrict__ v2s)          // [128][1024]
{
  __shared__ float As[2][2][32][12];
  __shared__ float Ws[2][2][32][66];
  __shared__ float fb[256][2];
  const int tid = threadIdx.x;
  const int p = tid >> 8;     // panel (0: k<512, 1: k>=512)
  const int q = tid & 255;
  const int b0 = (blockIdx.x >> 4) << 3;   // 16 b-tiles x 8
  const int o0 = (blockIdx.x & 15) << 6;   // 16 o-tiles x 64
  const int cm = q >> 5;            // compute: own row 0..7
  const int co = (q & 31) << 1;     // compute: own 2 cols
  const int am = q >> 5, ak = q & 31;        // A staging: 1 float
  const int wr = q >> 3, wk = (q & 7) << 2;  // W staging: rows wr, wr+32

  const float* Arow = prev + (size_t)(b0 + am) * prevStride + p * 512 + ak;
  const float* Wrow = W2b + (size_t)(o0 + wr) * 1024 + p * 512 + wk;
  const size_t WR32 = (size_t)32 * 1024;

  float pan0 = 0.f, pan1 = 0.f;
  // prologue
  {
    float a = Arow[0];
    float4 w0 = *(const float4*)(Wrow);
    float4 w1 = *(const float4*)(Wrow + WR32);
    r2_stage(As, Ws, p, 0, ak, am, wk, wr, a, w0, w1);
  }
  __syncthreads();
  int cb = 0;
  for (int kt = 0; kt < 16; ++kt) {
    float na; float4 nw0, nw1;
    if (kt < 15) {
      const int ko = (kt + 1) << 5;
      na = Arow[ko];
      nw0 = *(const float4*)(Wrow + ko);
      nw1 = *(const float4*)(Wrow + ko + WR32);
    }
#pragma unroll
    for (int k = 0; k < 32; ++k) {
      float a = As[p][cb][k][cm];
      float2 w = *(const float2*)&Ws[p][cb][k][co];
      pan0 = fmaf(a, w.x, pan0);
      pan1 = fmaf(a, w.y, pan1);
    }
    __syncthreads();
    if (kt < 15) r2_stage(As, Ws, p, cb ^ 1, ak, am, wk, wr, na, nw0, nw1);
    __syncthreads();
    cb ^= 1;
  }
  // fold panels in BLAS order: fadd(fadd(0, pan_low), pan_high)
  if (p == 1) { fb[q][0] = pan0; fb[q][1] = pan1; }
  __syncthreads();
  if (p == 0) {
    float r0 = __fadd_rn(__fadd_rn(0.f, pan0), fb[q][0]);
    float r1 = __fadd_rn(__fadd_rn(0.f, pan1), fb[q][1]);
    const int b = b0 + cm;
    const int o = o0 + co;
    float2 ca = *(const float2*)(curA + (size_t)b * bStride + o);
    float2 vv2 = *(float2*)(v2s + (size_t)b * 1024 + o);
    // reference: one __fadd_rn combining the two matmuls, W2a result first
    float cin0 = __fadd_rn(ca.x, r0);
    float cin1 = __fadd_rn(ca.y, r1);
    float vva = __fadd_rn(__fmul_rn(0.93f, vv2.x), cin0);
    float sa = (vva >= 0.5f) ? 1.0f : 0.0f;
    vv2.x = __fmul_rn(vva, __fsub_rn(1.0f, sa));
    float vvb = __fadd_rn(__fmul_rn(0.93f, vv2.y), cin1);
    float sb = (vvb >= 0.5f) ? 1.0f : 0.0f;
    vv2.y = __fmul_rn(vvb, __fsub_rn(1.0f, sb));
    *(float2*)(v2s + (size_t)b * 1024 + o) = vv2;
    float2 sv; sv.x = sa; sv.y = sb;
    *(float2*)(sOut + (size_t)b * bStride + o) = sv;
    if (writePrev) *(float2*)(sPrevOut + (size_t)b * 1024 + o) = sv;
  }
}

__global__ __launch_bounds__(256) void zero_kernel(float* __restrict__ p, int n) {
  int i = blockIdx.x * 256 + threadIdx.x;
  if (i < n) p[i] = 0.f;
}

// ---------------------------------------------------------------------------
// ----------------- FALLBACK: round-11 phase-pipelined path -----------------
// ---------------------------------------------------------------------------

enum : size_t {
  FOFF_V0  = 0,
  FOFF_V1  = FOFF_V0 + 128 * 1024,
  FOFF_V2  = FOFF_V1 + 128 * 1024,
  FOFF_V3  = FOFF_V2 + 128 * 1024,
  FOFF_VO  = FOFF_V3 + 128 * 512,
  FOFF_CNT = FOFF_VO + 128 * 128,
  FOFF_S0  = FOFF_CNT + 128 * 128,
  FOFF_S1  = FOFF_S0 + 2 * 128 * 1024,
  FOFF_S2  = FOFF_S1 + 2 * 128 * 1024,
  FOFF_S3  = FOFF_S2 + 2 * 128 * 1024,
  WS_FLOATS = FOFF_S3 + 2 * 128 * 512
};

__global__ __launch_bounds__(256) void init_kernel(float* __restrict__ wf) {
  size_t i = (size_t)blockIdx.x * blockDim.x + threadIdx.x;
  size_t stride = (size_t)gridDim.x * blockDim.x;
  for (size_t j = i; j < WS_FLOATS; j += stride) wf[j] = 0.0f;
}

__device__ __forceinline__ bool is_fold(int K, int k0) {
  return (K == 1024) && (k0 == 512);
}

__device__ __forceinline__ void gemm_blas(
    const float* __restrict__ Abase, int Astride,
    const float* __restrict__ Wbase, int K,
    int bBase, int oBase,
    float (&As)[32][33], float (&Ws)[32][33],
    float acc[2][2])
{
  const int tid = threadIdx.x;
  const int ldRow = tid >> 3;
  const int ldK   = (tid & 7) << 2;
  const int tb = (tid & 15) << 1;
  const int to = (tid >> 4) << 1;
  float tot[2][2]  = {{0.f, 0.f}, {0.f, 0.f}};
  float pan[2][2]  = {{0.f, 0.f}, {0.f, 0.f}};
  for (int k0 = 0; k0 < K; k0 += 32) {
    if (is_fold(K, k0)) {
#pragma unroll
      for (int i = 0; i < 2; ++i)
#pragma unroll
        for (int j = 0; j < 2; ++j) {
          tot[i][j] = __fadd_rn(tot[i][j], pan[i][j]);
          pan[i][j] = 0.f;
        }
    }
    float4 av = *(const float4*)(Abase + (size_t)(bBase + ldRow) * Astride + k0 + ldK);
    float4 wv = *(const float4*)(Wbase + (size_t)(oBase + ldRow) * K       + k0 + ldK);
    As[ldK + 0][ldRow] = av.x; As[ldK + 1][ldRow] = av.y;
    As[ldK + 2][ldRow] = av.z; As[ldK + 3][ldRow] = av.w;
    Ws[ldK + 0][ldRow] = wv.x; Ws[ldK + 1][ldRow] = wv.y;
    Ws[ldK + 2][ldRow] = wv.z; Ws[ldK + 3][ldRow] = wv.w;
    __syncthreads();
#pragma unroll
    for (int k = 0; k < 32; ++k) {
      float a0 = As[k][tb], a1 = As[k][tb + 1];
      float w0 = Ws[k][to], w1 = Ws[k][to + 1];
      pan[0][0] = fmaf(a0, w0, pan[0][0]);
      pan[0][1] = fmaf(a0, w1, pan[0][1]);
      pan[1][0] = fmaf(a1, w0, pan[1][0]);
      pan[1][1] = fmaf(a1, w1, pan[1][1]);
    }
    __syncthreads();
  }
#pragma unroll
  for (int i = 0; i < 2; ++i)
#pragma unroll
    for (int j = 0; j < 2; ++j)
      acc[i][j] = __fadd_rn(tot[i][j], pan[i][j]);
}

__global__ __launch_bounds__(256) void phase_kernel(
    const float* __restrict__ x,
    const float* __restrict__ W0, const float* __restrict__ W1,
    const float* __restrict__ W2a, const float* __restrict__ W2b,
    const float* __restrict__ W3, const float* __restrict__ W4,
    float* __restrict__ wf, float* __restrict__ out, int p)
{
  float* counts = wf + FOFF_CNT;
  float* s0 = wf + FOFF_S0;  float* s1 = wf + FOFF_S1;
  float* s2 = wf + FOFF_S2;  float* s3 = wf + FOFF_S3;
  const int cur = p & 1, prev = cur ^ 1;

  const int blk = blockIdx.x;
  int layer, lb, K, N, t;
  if (blk < 128)      { layer = 0; lb = blk;       t = p;     K = 512;  N = 1024; }
  else if (blk < 256) { layer = 1; lb = blk - 128; t = p - 1; K = 1024; N = 1024; }
  else if (blk < 384) { layer = 2; lb = blk - 256; t = p - 2; K = 1024; N = 1024; }
  else if (blk < 448) { layer = 3; lb = blk - 384; t = p - 3; K = 1024; N = 512;  }
  else                { layer = 4; lb = blk - 448; t = p - 4; K = 512;  N = 128;  }
  if (t < 0 || t >= NT) return;

  const int ntO = N >> 5;
  const int bBase = (lb / ntO) << 5;
  const int oBase = (lb % ntO) << 5;

  const float* A; int Astride;
  const float* Wm; float* v; float* sOut = nullptr;
  float alpha, vth;
  switch (layer) {
    case 0: A = x + (size_t)t * 512; Astride = NT * 512; Wm = W0; v = wf + FOFF_V0;
            alpha = 0.9f;  vth = 0.5f; sOut = s0 + (size_t)cur * 128 * 1024; break;
    case 1: A = s0 + (size_t)prev * 128 * 1024; Astride = 1024; Wm = W1; v = wf + FOFF_V1;
            alpha = 0.95f; vth = 0.5f; sOut = s1 + (size_t)cur * 128 * 1024; break;
    case 2: A = s1 + (size_t)prev * 128 * 1024; Astride = 1024; Wm = W2a; v = wf + FOFF_V2;
            alpha = 0.93f; vth = 0.5f; sOut = s2 + (size_t)cur * 128 * 1024; break;
    case 3: A = s2 + (size_t)prev * 128 * 1024; Astride = 1024; Wm = W3; v = wf + FOFF_V3;
            alpha = 0.9f;  vth = 0.5f; sOut = s3 + (size_t)cur * 128 * 512; break;
    default: A = s3 + (size_t)prev * 128 * 512; Astride = 512; Wm = W4; v = wf + FOFF_VO;
            alpha = 0.82f; vth = 0.8f; break;
  }

  __shared__ float As[32][33];
  __shared__ float Ws[32][33];
  float acc[2][2];

  gemm_blas(A, Astride, Wm, K, bBase, oBase, As, Ws, acc);

  float acc2[2][2];
  if (layer == 2) {
    gemm_blas(s2 + (size_t)prev * 128 * 1024, 1024, W2b, 1024, bBase, oBase, As, Ws, acc2);
  }

  const int tid = threadIdx.x;
  const int tb = (tid & 15) << 1;
  const int to = (tid >> 4) << 1;
#pragma unroll
  for (int i = 0; i < 2; ++i) {
#pragma unroll
    for (int j = 0; j < 2; ++j) {
      const int b = bBase + tb + i;
      const int o = oBase + to + j;
      float cur_in = acc[i][j];
      if (layer == 2) cur_in = __fadd_rn(acc[i][j], acc2[i][j]);
      float* vp = v + (size_t)b * N + o;
      float vv = __fadd_rn(__fmul_rn(alpha, *vp), cur_in);
      float s = (vv >= vth) ? 1.0f : 0.0f;
      *vp = __fmul_rn(vv, __fsub_rn(1.0f, s));
      if (layer < 4) {
        sOut[(size_t)b * N + o] = s;
      } else {
        out[(size_t)b * (NT * 128) + (size_t)t * 128 + o] = s;
        counts[b * 128 + o] = __fadd_rn(counts[b * 128 + o], s);
      }
    }
  }
}

__global__ __launch_bounds__(256) void fin_kernel(const float* __restrict__ counts,
                                                  float* __restrict__ out) {
  int i = blockIdx.x * blockDim.x + threadIdx.x;
  if (i < 128 * 128) out[(size_t)128 * NT * 128 + i] = counts[i];
}

// ---------------------------------------------------------------------------
// -------------------------------- launcher ---------------------------------
// ---------------------------------------------------------------------------

extern "C" void kernel_launch(void* const* d_in, const int* in_sizes, int n_in,
                              void* d_out, int out_size, void* d_ws, size_t ws_size,
                              hipStream_t stream) {
  const float* x   = (const float*)d_in[0];
  const float* W0  = (const float*)d_in[1];
  const float* W1  = (const float*)d_in[2];
  const float* W2a = (const float*)d_in[3];
  const float* W2b = (const float*)d_in[4];
  const float* W3  = (const float*)d_in[5];
  const float* W4  = (const float*)d_in[6];
  float* wf  = (float*)d_ws;
  float* out = (float*)d_out;

  // state: v0,v1,v2 [128*1024] + v3 [128*512] + vo,cnt [128*128] + sprev [128*1024]
  const size_t STATE_F = 3 * 131072 + 65536 + 2 * 16384 + 131072;  // 622592 floats

  int Tc = 0;
  const int cands[8] = {512, 256, 128, 64, 32, 16, 8, 2};
  for (int ci = 0; ci < 8; ++ci) {
    size_t need = (STATE_F + 2ull * 128 * cands[ci] * 1024) * sizeof(float);
    if (ws_size >= need) { Tc = cands[ci]; break; }
  }

  if (Tc) {
    float* v0s   = wf;
    float* v1s   = wf + 131072;
    float* v2s   = wf + 262144;
    float* v3s   = wf + 393216;
    float* vos   = wf + 458752;
    float* cnts  = wf + 475136;
    float* sprev = wf + 491520;
    float* CUR   = wf + STATE_F;
    float* SP    = CUR + (size_t)128 * Tc * 1024;
    const size_t bStride = (size_t)Tc * 1024;

    int tcshift = 0;
    while ((1 << tcshift) < Tc) ++tcshift;

    zero_kernel<<<(int)((STATE_F + 255) / 256), 256, 0, stream>>>(wf, (int)STATE_F);

    const int gy = 2 * Tc;  // (128*Tc)/64 M-tiles
    for (int t0 = 0; t0 < NT; t0 += Tc) {
      // L0: cur0 = x @ W0^T   (K=512, no fold), row-mapped read from x
      big_gemm<512, false, true><<<dim3(8, gy), 256, 0, stream>>>(x, W0, CUR, 1024, t0, tcshift);
      scan_kernel<1024><<<512, 256, 0, stream>>>(CUR, SP, v0s, 0.9f, 0.5f, Tc);
      // L1: cur1 = s0 @ W1^T  (K=1024, fold@512)
      big_gemm<1024, true, false><<<dim3(8, gy), 256, 0, stream>>>(SP, W1, CUR, 1024, 0, 0);
      scan_kernel<1024><<<512, 256, 0, stream>>>(CUR, SP, v1s, 0.95f, 0.5f, Tc);
      // L2a: cur2a = s1 @ W2a^T
      big_gemm<1024, true, false><<<dim3(8, gy), 256, 0, stream>>>(SP, W2a, CUR, 1024, 0, 0);
      // L2 recurrent: per-step GEMM + fused LIF; s2 -> SP rows (b, tl)
      for (int tl = 0; tl < Tc; ++tl) {
        const float* prev = (tl == 0) ? sprev : (SP + (size_t)(tl - 1) * 1024);
        size_t prevStride = (tl == 0) ? (size_t)1024 : bStride;
        rec2_kernel<<<256, 512, 0, stream>>>(
            CUR + (size_t)tl * 1024, W2b, prev, prevStride,
            SP + (size_t)tl * 1024, bStride,
            sprev, (tl == Tc - 1) ? 1 : 0, v2s);
      }
      // L3: cur3 = s2 @ W3^T  (N=512)
      big_gemm<1024, true, false><<<dim3(4, gy), 256, 0, stream>>>(SP, W3, CUR, 512, 0, 0);
      scan_kernel<512><<<256, 256, 0, stream>>>(CUR, SP, v3s, 0.9f, 0.5f, Tc);
      // L4: cur4 = s3 @ W4^T  (K=512, N=128)
      big_gemm<512, false, false><<<dim3(1, gy), 256, 0, stream>>>(SP, W4, CUR, 128, 0, 0);
      scan_out_kernel<<<64, 256, 0, stream>>>(CUR, out, vos, cnts, t0, Tc);
    }
    fin_kernel<<<64, 256, 0, stream>>>(cnts, out);
  } else {
    // fallback: round-11 phase-pipelined path (requires only 5.64 MB)
    init_kernel<<<256, 256, 0, stream>>>(wf);
    for (int p = 0; p < NT + 4; ++p) {
      phase_kernel<<<464, 256, 0, stream>>>(x, W0, W1, W2a, W2b, W3, W4, wf, out, p);
    }
    fin_kernel<<<64, 256, 0, stream>>>(wf + FOFF_CNT, out);
  }
}

// Round 3
// 24205.624 us; speedup vs baseline: 4.0833x; 4.0833x over previous
//
#include <hip/hip_runtime.h>
#include <cstddef>

// SafetyReflexSNN: 5-layer LIF SNN, B=128, T=512.
//
// ROUND 14: phase-pipelined (round-11 macro-structure) with a rebuilt
// per-phase kernel. Workspace evidence: ws_size in [4.59, 10.9) MB
// (round-13's Tc=2 selection), so this path uses 3.93 MB total:
// spikes stored as BYTES (0/1, exact under uchar->float conversion).
//
// Changes vs round-11 (all numerics-preserving):
//  - Layer 2 split into two pipeline stages: 2a = s1@W2a (pure GEMM ->
//    float buffer), 2b = s2_prev@W2b + ONE __fadd_rn(cur2a, rec) + LIF.
//    Same operand order as round-11's __fadd_rn(acc, acc2) -> bit-identical.
//    Per-phase critical path: 2 chained K=1024 GEMMs -> 1.
//  - GEMM: 2-deep register prefetch + LDS double-buffer, ONE barrier per
//    k-tile (global-load latency hidden under compute).
//  - LDS pad 33->34 so float2 (b64) compute reads are aligned+conflict-free.
//  - Pipeline depth 6: L0(t=p) L1(p-1) 2a(p-2) 2b(p-3) L3(p-4) L4(p-5);
//    517 phases. Spike/cur2a buffers double-buffered by phase parity.
//
// NUMERICS (absmax 0.0 inherited): per output element, op sequence is
// IDENTICAL to round-11: ascending-k fmaf chain per accumulator; K=1024
// folds once at k=512 via tot=__fadd_rn(tot,pan); final __fadd_rn(tot,pan);
// layer-2 combine = one __fadd_rn(W2a_res, W2b_res); LIF = __fmul_rn /
// __fadd_rn / __fsub_rn; counts accumulated in ascending t.

#define NB 128
#define NT 512

// ---- workspace layout (floats) ----
enum : size_t {
  OFF_V0   = 0,                       // [128][1024]
  OFF_V1   = OFF_V0 + 131072,
  OFF_V2   = OFF_V1 + 131072,
  OFF_V3   = OFF_V2 + 131072,         // [128][512]
  OFF_VO   = OFF_V3 + 65536,          // [128][128]
  OFF_CNT  = OFF_VO + 16384,          // [128][128]
  OFF_C2A  = OFF_CNT + 16384,         // 2 x [128][1024] float
  OFF_BYTE = OFF_C2A + 262144,        // byte region starts here (float idx)
  // byte offsets within byte region:
  //   s0: 2x131072 B @0, s1: @262144, s2: @524288, s3: 2x65536 B @786432
  WS_FLOATS = OFF_BYTE + 229376       // 983040 floats = 3.93 MB
};
#define BS0 0
#define BS1 262144
#define BS2 524288
#define BS3 786432

__global__ __launch_bounds__(256) void init_kernel(float* __restrict__ wf) {
  size_t i = (size_t)blockIdx.x * blockDim.x + threadIdx.x;
  size_t stride = (size_t)gridDim.x * blockDim.x;
  for (size_t j = i; j < WS_FLOATS; j += stride) wf[j] = 0.0f;
}

// ---- GEMM core: 32x32 tile, 256 thr, 2x2/thread, K in {512,1024}.
// LDS double-buffer, 2-deep register prefetch, ONE barrier per k-tile.
// Per accumulator: ascending-k fmaf chain; optional fold at k=512.
template<bool ABYTE>
__device__ __forceinline__ void gemm_core(
    const void* __restrict__ Abase, int Astride,
    const float* __restrict__ W, int K, int fold,
    int bBase, int oBase,
    float (&As)[2][32][34], float (&Ws)[2][32][34],
    float acc[2][2])
{
  const int tid = threadIdx.x;
  const int ldRow = tid >> 3;        // 0..31
  const int ldK   = (tid & 7) << 2;  // 0,4..28
  const int tb = (tid & 15) << 1;
  const int to = (tid >> 4) << 1;

  const float* Wrow = W + (size_t)(oBase + ldRow) * K + ldK;
  const unsigned char* Abrow = nullptr;
  const float* Afrow = nullptr;
  if (ABYTE) Abrow = (const unsigned char*)Abase + (size_t)(bBase + ldRow) * Astride + ldK;
  else       Afrow = (const float*)Abase + (size_t)(bBase + ldRow) * Astride + ldK;

  const int NKT = K >> 5;

  float pa[4]; float4 pw;  // tile kt+1, staged next
  // tile 0 -> LDS buf 0
  {
    float c0, c1, c2, c3;
    if (ABYTE) {
      unsigned int u = *(const unsigned int*)(Abrow);
      c0 = (float)(u & 0xff); c1 = (float)((u >> 8) & 0xff);
      c2 = (float)((u >> 16) & 0xff); c3 = (float)(u >> 24);
    } else {
      float4 f = *(const float4*)(Afrow);
      c0 = f.x; c1 = f.y; c2 = f.z; c3 = f.w;
    }
    float4 cw = *(const float4*)(Wrow);
    As[0][ldK + 0][ldRow] = c0; As[0][ldK + 1][ldRow] = c1;
    As[0][ldK + 2][ldRow] = c2; As[0][ldK + 3][ldRow] = c3;
    Ws[0][ldK + 0][ldRow] = cw.x; Ws[0][ldK + 1][ldRow] = cw.y;
    Ws[0][ldK + 2][ldRow] = cw.z; Ws[0][ldK + 3][ldRow] = cw.w;
  }
  // tile 1 -> regs
  if (NKT > 1) {
    if (ABYTE) {
      unsigned int u = *(const unsigned int*)(Abrow + 32);
      pa[0] = (float)(u & 0xff); pa[1] = (float)((u >> 8) & 0xff);
      pa[2] = (float)((u >> 16) & 0xff); pa[3] = (float)(u >> 24);
    } else {
      float4 f = *(const float4*)(Afrow + 32);
      pa[0] = f.x; pa[1] = f.y; pa[2] = f.z; pa[3] = f.w;
    }
    pw = *(const float4*)(Wrow + 32);
  }
  __syncthreads();

  float tot[2][2] = {{0.f, 0.f}, {0.f, 0.f}};
  float pan[2][2] = {{0.f, 0.f}, {0.f, 0.f}};
  int cb = 0;
  for (int kt = 0; kt < NKT; ++kt) {
    float na[4]; float4 nw;
    if (kt + 2 < NKT) {  // 2-deep prefetch: tile kt+2 -> regs
      const int ko = (kt + 2) << 5;
      if (ABYTE) {
        unsigned int u = *(const unsigned int*)(Abrow + ko);
        na[0] = (float)(u & 0xff); na[1] = (float)((u >> 8) & 0xff);
        na[2] = (float)((u >> 16) & 0xff); na[3] = (float)(u >> 24);
      } else {
        float4 f = *(const float4*)(Afrow + ko);
        na[0] = f.x; na[1] = f.y; na[2] = f.z; na[3] = f.w;
      }
      nw = *(const float4*)(Wrow + ko);
    }
    if (fold && kt == 16) {  // kc-panel boundary at k=512
#pragma unroll
      for (int i = 0; i < 2; ++i)
#pragma unroll
        for (int j = 0; j < 2; ++j) {
          tot[i][j] = __fadd_rn(tot[i][j], pan[i][j]);
          pan[i][j] = 0.f;
        }
    }
#pragma unroll
    for (int k = 0; k < 32; ++k) {
      const float2 a = *(const float2*)&As[cb][k][tb];
      const float2 w = *(const float2*)&Ws[cb][k][to];
      pan[0][0] = fmaf(a.x, w.x, pan[0][0]);
      pan[0][1] = fmaf(a.x, w.y, pan[0][1]);
      pan[1][0] = fmaf(a.y, w.x, pan[1][0]);
      pan[1][1] = fmaf(a.y, w.y, pan[1][1]);
    }
    // write tile kt+1 into the buffer last read at kt-1 (safe: barrier at
    // end of kt-1 ensured all reads done). Single barrier publishes it.
    if (kt + 1 < NKT) {
      const int nb = cb ^ 1;
      As[nb][ldK + 0][ldRow] = pa[0]; As[nb][ldK + 1][ldRow] = pa[1];
      As[nb][ldK + 2][ldRow] = pa[2]; As[nb][ldK + 3][ldRow] = pa[3];
      Ws[nb][ldK + 0][ldRow] = pw.x; Ws[nb][ldK + 1][ldRow] = pw.y;
      Ws[nb][ldK + 2][ldRow] = pw.z; Ws[nb][ldK + 3][ldRow] = pw.w;
    }
    if (kt + 2 < NKT) { pa[0] = na[0]; pa[1] = na[1]; pa[2] = na[2]; pa[3] = na[3]; pw = nw; }
    __syncthreads();
    cb ^= 1;
  }
#pragma unroll
  for (int i = 0; i < 2; ++i)
#pragma unroll
    for (int j = 0; j < 2; ++j)
      acc[i][j] = __fadd_rn(tot[i][j], pan[i][j]);  // fold last panel
}

// Blocks: L0 [0,128) L1 [128,256) 2a [256,384) 2b [384,512) L3 [512,576) L4 [576,592)
__global__ __launch_bounds__(256) void phase_kernel(
    const float* __restrict__ x,
    const float* __restrict__ W0, const float* __restrict__ W1,
    const float* __restrict__ W2a, const float* __restrict__ W2b,
    const float* __restrict__ W3, const float* __restrict__ W4,
    float* __restrict__ wf, float* __restrict__ out, int p)
{
  float* cnt = wf + OFF_CNT;
  float* c2a = wf + OFF_C2A;
  unsigned char* sb = (unsigned char*)(wf + OFF_BYTE);
  const int cur = p & 1, prev = cur ^ 1;

  const int blk = blockIdx.x;
  int g, lb, t, K, N, fold;
  if (blk < 128)      { g = 0; lb = blk;       t = p;     K = 512;  N = 1024; fold = 0; }
  else if (blk < 256) { g = 1; lb = blk - 128; t = p - 1; K = 1024; N = 1024; fold = 1; }
  else if (blk < 384) { g = 2; lb = blk - 256; t = p - 2; K = 1024; N = 1024; fold = 1; }
  else if (blk < 512) { g = 3; lb = blk - 384; t = p - 3; K = 1024; N = 1024; fold = 1; }
  else if (blk < 576) { g = 4; lb = blk - 512; t = p - 4; K = 1024; N = 512;  fold = 1; }
  else                { g = 5; lb = blk - 576; t = p - 5; K = 512;  N = 128;  fold = 0; }
  if (t < 0 || t >= NT) return;

  const int ntO = N >> 5;
  const int bBase = (lb / ntO) << 5;
  const int oBase = (lb % ntO) << 5;

  const float* Wm; const void* Ab; int Astride;
  switch (g) {
    case 0: Wm = W0;  Ab = x + (size_t)t * 512;              Astride = NT * 512; break;
    case 1: Wm = W1;  Ab = sb + BS1 - BS1 + (size_t)prev * 131072; Astride = 1024; break; // s0
    case 2: Wm = W2a; Ab = sb + BS1 + (size_t)prev * 131072; Astride = 1024; break;       // s1
    case 3: Wm = W2b; Ab = sb + BS2 + (size_t)prev * 131072; Astride = 1024; break;       // s2
    case 4: Wm = W3;  Ab = sb + BS2 + (size_t)prev * 131072; Astride = 1024; break;       // s2
    default: Wm = W4; Ab = sb + BS3 + (size_t)prev * 65536;  Astride = 512;  break;       // s3
  }

  __shared__ float As[2][32][34];
  __shared__ float Ws[2][32][34];
  float acc[2][2];
  if (g == 0) gemm_core<false>(Ab, Astride, Wm, K, fold, bBase, oBase, As, Ws, acc);
  else        gemm_core<true >(Ab, Astride, Wm, K, fold, bBase, oBase, As, Ws, acc);

  const int tid = threadIdx.x;
  const int tb = (tid & 15) << 1;
  const int to = (tid >> 4) << 1;

  if (g == 2) {
    // stage 2a: store gemm result (exact) for next phase's 2b combine
    float* dst = c2a + (size_t)cur * 131072;
#pragma unroll
    for (int i = 0; i < 2; ++i) {
      const int b = bBase + tb + i;
      float2 st; st.x = acc[i][0]; st.y = acc[i][1];
      *(float2*)(dst + (size_t)b * 1024 + oBase + to) = st;
    }
    return;
  }

  float alpha, vth = 0.5f;
  float* v; unsigned char* sOut = nullptr;
  switch (g) {
    case 0: alpha = 0.90f; v = wf + OFF_V0; sOut = sb + BS0 + (size_t)cur * 131072; break;
    case 1: alpha = 0.95f; v = wf + OFF_V1; sOut = sb + BS1 + (size_t)cur * 131072; break;
    case 3: alpha = 0.93f; v = wf + OFF_V2; sOut = sb + BS2 + (size_t)cur * 131072; break;
    case 4: alpha = 0.90f; v = wf + OFF_V3; sOut = sb + BS3 + (size_t)cur * 65536;  break;
    default: alpha = 0.82f; vth = 0.8f; v = wf + OFF_VO; break;  // g==5
  }
  const float* c2aPrev = c2a + (size_t)prev * 131072;

#pragma unroll
  for (int i = 0; i < 2; ++i) {
    const int b = bBase + tb + i;
    int si[2];
#pragma unroll
    for (int j = 0; j < 2; ++j) {
      const int o = oBase + to + j;
      float cin = acc[i][j];
      if (g == 3)  // reference: ONE __fadd_rn, W2a result first
        cin = __fadd_rn(c2aPrev[(size_t)b * 1024 + o], acc[i][j]);
      float* vp = v + (size_t)b * N + o;
      // numpy: mul rounded, then add rounded — NO fma
      float vv = __fadd_rn(__fmul_rn(alpha, *vp), cin);
      int s = (vv >= vth) ? 1 : 0;
      float sf = (float)s;
      *vp = __fmul_rn(vv, __fsub_rn(1.0f, sf));
      si[j] = s;
      if (g == 5) {
        out[(size_t)b * (NT * 128) + (size_t)t * 128 + o] = sf;
        cnt[b * 128 + o] = __fadd_rn(cnt[b * 128 + o], sf);  // integer-exact
      }
    }
    if (g != 5) {
      *(unsigned short*)(sOut + (size_t)b * N + oBase + to) =
          (unsigned short)(si[0] | (si[1] << 8));
    }
  }
}

__global__ __launch_bounds__(256) void fin_kernel(const float* __restrict__ counts,
                                                  float* __restrict__ out) {
  int i = blockIdx.x * blockDim.x + threadIdx.x;
  if (i < 128 * 128) out[(size_t)128 * NT * 128 + i] = counts[i];
}

extern "C" void kernel_launch(void* const* d_in, const int* in_sizes, int n_in,
                              void* d_out, int out_size, void* d_ws, size_t ws_size,
                              hipStream_t stream) {
  const float* x   = (const float*)d_in[0];
  const float* W0  = (const float*)d_in[1];
  const float* W1  = (const float*)d_in[2];
  const float* W2a = (const float*)d_in[3];
  const float* W2b = (const float*)d_in[4];
  const float* W3  = (const float*)d_in[5];
  const float* W4  = (const float*)d_in[6];
  float* wf  = (float*)d_ws;
  float* out = (float*)d_out;

  init_kernel<<<512, 256, 0, stream>>>(wf);
  // pipeline depth 6: phases 0 .. NT+4 (t = p-5 for L4)
  for (int p = 0; p < NT + 5; ++p) {
    phase_kernel<<<592, 256, 0, stream>>>(x, W0, W1, W2a, W2b, W3, W4, wf, out, p);
  }
  fin_kernel<<<64, 256, 0, stream>>>(wf + OFF_CNT, out);
}